// Round 1
// baseline (1832.791 us; speedup 1.0000x reference)
//
#include <hip/hip_runtime.h>
#include <math.h>

// Residual VQ: x (262144,128) fp32, codebooks (3,256,128) fp32.
// Output: [indices as float (262144*3)] ++ [quantized (262144*128)].
//
// ARITHMETIC CONTRACT (round 3, absmax=0 — do not change):
//   M_k  = OpenBLAS sgemm K-loop: sequential FMA chain j=0..127, acc init 0
//   A    = np.sum(r*r): pairwise_sum 8-accumulator scheme, products rounded
//          separately (fmaf(x,x,0) = single-rounded product, blocks fusion)
//   d2_k = (A - 2.0f*M_k) + B_k ; argmin strict < ascending k
//   residual -= q ; quantized = (q0 + q1) + q2  (elementwise fp32, ref order)
//
// ROUND 5 CHANGE: residual as 32 NAMED float4 SSA variables (macro-expanded),
// zero arrays touched by the hot path. Round 4 still showed VGPR_Count=104
// (< 128 needed for r[]) -> the float r[128] alloca was never promoted (SROA
// runs pre-unroll; PromoteAlloca rejects 128-elem arrays), so every FMA read
// its operand from scratch => latency-bound at VALUBusy 39%. Named scalars
// are SSA from the front-end: regalloc MUST keep them in VGPRs (cap 256 via
// __launch_bounds__(256,2), usage ~170 -> no spill). Codebook reads stay
// wave-uniform -> s_load (scalar pipe, free vs VALU; 1 SGPR/VALU-op is legal).

constexpr int kItems = 262144;
constexpr int kDim   = 128;
constexpr int kNcb   = 3;
constexpr int kK     = 256;
constexpr int kBlock = 256;

__device__ __forceinline__ float sq_rn(float x) {
    return __builtin_fmaf(x, x, 0.0f);
}

// numpy pairwise_sum, n=128: 8 accumulators, acc_j = v[j]+v[j+8]+...+v[j+120],
// combined ((r0+r1)+(r2+r3))+((r4+r5)+(r6+r7)).
// Used ONLY for the LDS B-table (global-memory rows; no local array involved).
template <typename F>
__device__ __forceinline__ float np_pairwise128(F term) {
    float r0 = term(0), r1 = term(1), r2 = term(2), r3 = term(3),
          r4 = term(4), r5 = term(5), r6 = term(6), r7 = term(7);
    #pragma unroll
    for (int i = 8; i < 128; i += 8) {
        r0 = r0 + term(i + 0); r1 = r1 + term(i + 1);
        r2 = r2 + term(i + 2); r3 = r3 + term(i + 3);
        r4 = r4 + term(i + 4); r5 = r5 + term(i + 5);
        r6 = r6 + term(i + 6); r7 = r7 + term(i + 7);
    }
    return ((r0 + r1) + (r2 + r3)) + ((r4 + r5) + (r6 + r7));
}

#define X32(X) X(0) X(1) X(2) X(3) X(4) X(5) X(6) X(7) \
  X(8) X(9) X(10) X(11) X(12) X(13) X(14) X(15) \
  X(16) X(17) X(18) X(19) X(20) X(21) X(22) X(23) \
  X(24) X(25) X(26) X(27) X(28) X(29) X(30) X(31)

// A = np.sum(r*r) pairwise step: terms 8e..8e+7 -> acc0..7 (e even chunk, o=e+1)
#define ASTEP(e, o) \
    a0 = a0 + sq_rn(r##e.x); a1 = a1 + sq_rn(r##e.y); \
    a2 = a2 + sq_rn(r##e.z); a3 = a3 + sq_rn(r##e.w); \
    a4 = a4 + sq_rn(r##o.x); a5 = a5 + sq_rn(r##o.y); \
    a6 = a6 + sq_rn(r##o.z); a7 = a7 + sq_rn(r##o.w);

// one j-chunk (4 dims) of the 4 sequential FMA chains; chain order = j ascending
#define FSTEP(i) { \
    const float4 w0 = cc0[i]; \
    const float4 w1 = cc1[i]; \
    const float4 w2 = cc2[i]; \
    const float4 w3 = cc3[i]; \
    m0 = __builtin_fmaf(r##i.x, w0.x, m0); m0 = __builtin_fmaf(r##i.y, w0.y, m0); \
    m0 = __builtin_fmaf(r##i.z, w0.z, m0); m0 = __builtin_fmaf(r##i.w, w0.w, m0); \
    m1 = __builtin_fmaf(r##i.x, w1.x, m1); m1 = __builtin_fmaf(r##i.y, w1.y, m1); \
    m1 = __builtin_fmaf(r##i.z, w1.z, m1); m1 = __builtin_fmaf(r##i.w, w1.w, m1); \
    m2 = __builtin_fmaf(r##i.x, w2.x, m2); m2 = __builtin_fmaf(r##i.y, w2.y, m2); \
    m2 = __builtin_fmaf(r##i.z, w2.z, m2); m2 = __builtin_fmaf(r##i.w, w2.w, m2); \
    m3 = __builtin_fmaf(r##i.x, w3.x, m3); m3 = __builtin_fmaf(r##i.y, w3.y, m3); \
    m3 = __builtin_fmaf(r##i.z, w3.z, m3); m3 = __builtin_fmaf(r##i.w, w3.w, m3); }

// residual update: r[j] = r[j] - cw[j], fp32, ref order
#define RSUB(i) { const float4 w = cwv[i]; \
    r##i.x = r##i.x - w.x; r##i.y = r##i.y - w.y; \
    r##i.z = r##i.z - w.z; r##i.w = r##i.w - w.w; }

__global__ __launch_bounds__(kBlock, 2) void rvq_kernel(
    const float* __restrict__ x,
    const float* __restrict__ cb,
    float* __restrict__ out)
{
    // B_k = np.sum(cb*cb, axis=-1), bit-exact, staged in LDS
    __shared__ float s_B[kNcb * kK];
    for (int m = threadIdx.x; m < kNcb * kK; m += kBlock) {
        const float* row = cb + (size_t)m * kDim;
        s_B[m] = np_pairwise128([&](int j) { return sq_rn(row[j]); });
    }
    __syncthreads();

    const int item = blockIdx.x * kBlock + threadIdx.x;
    const float4* xv = (const float4*)(x + (size_t)item * kDim);

    // residual as 32 named float4 SSA values — never an alloca
#define DECLR(i) float4 r##i = xv[i];
    X32(DECLR)
#undef DECLR

    int sel0 = 0, sel1 = 0, sel2 = 0;

    for (int c = 0; c < kNcb; ++c) {
        const float* cbase = cb + (size_t)c * kK * kDim;

        // A = np.sum(r*r), numpy pairwise 8-accumulator scheme
        float a0 = sq_rn(r0.x), a1 = sq_rn(r0.y), a2 = sq_rn(r0.z), a3 = sq_rn(r0.w);
        float a4 = sq_rn(r1.x), a5 = sq_rn(r1.y), a6 = sq_rn(r1.z), a7 = sq_rn(r1.w);
        ASTEP(2,3)   ASTEP(4,5)   ASTEP(6,7)   ASTEP(8,9)
        ASTEP(10,11) ASTEP(12,13) ASTEP(14,15) ASTEP(16,17)
        ASTEP(18,19) ASTEP(20,21) ASTEP(22,23) ASTEP(24,25)
        ASTEP(26,27) ASTEP(28,29) ASTEP(30,31)
        const float A = ((a0 + a1) + (a2 + a3)) + ((a4 + a5) + (a6 + a7));

        float best = INFINITY;
        int bi = 0;
        // 4 independent sequential-FMA chains (ILP over the 4-cyc FMA latency);
        // codebook pointers are wave-uniform -> scalar loads
        for (int k = 0; k < kK; k += 4) {
            const float4* cc0 = (const float4*)(cbase + (size_t)(k + 0) * kDim);
            const float4* cc1 = (const float4*)(cbase + (size_t)(k + 1) * kDim);
            const float4* cc2 = (const float4*)(cbase + (size_t)(k + 2) * kDim);
            const float4* cc3 = (const float4*)(cbase + (size_t)(k + 3) * kDim);
            float m0 = 0.f, m1 = 0.f, m2 = 0.f, m3 = 0.f;
            X32(FSTEP)
            float t0 = (A - 2.0f * m0) + s_B[c * kK + k + 0];
            float t1 = (A - 2.0f * m1) + s_B[c * kK + k + 1];
            float t2 = (A - 2.0f * m2) + s_B[c * kK + k + 2];
            float t3 = (A - 2.0f * m3) + s_B[c * kK + k + 3];
            if (t0 < best) { best = t0; bi = k + 0; }
            if (t1 < best) { best = t1; bi = k + 1; }
            if (t2 < best) { best = t2; bi = k + 2; }
            if (t3 < best) { best = t3; bi = k + 3; }
        }
        if (c == 0) sel0 = bi; else if (c == 1) sel1 = bi; else sel2 = bi;

        const float4* cwv = (const float4*)(cbase + (size_t)bi * kDim);
        X32(RSUB)
    }

    // --- outputs
    float* out_idx = out;                             // (items, 3) as float
    float* out_q   = out + (size_t)kItems * kNcb;     // (items, 128)
    out_idx[(size_t)item * kNcb + 0] = (float)sel0;
    out_idx[(size_t)item * kNcb + 1] = (float)sel1;
    out_idx[(size_t)item * kNcb + 2] = (float)sel2;

    const float4* q0v = (const float4*)(cb + ((size_t)0 * kK + sel0) * kDim);
    const float4* q1v = (const float4*)(cb + ((size_t)1 * kK + sel1) * kDim);
    const float4* q2v = (const float4*)(cb + ((size_t)2 * kK + sel2) * kDim);
    float4* qov = (float4*)(out_q + (size_t)item * kDim);
    #pragma unroll
    for (int i = 0; i < kDim / 4; ++i) {
        const float4 u = q0v[i], v = q1v[i], w = q2v[i];
        float4 o;
        o.x = (u.x + v.x) + w.x;
        o.y = (u.y + v.y) + w.y;
        o.z = (u.z + v.z) + w.z;
        o.w = (u.w + v.w) + w.w;
        qov[i] = o;   // ((0+q0)+q1)+q2 in fp32, ref order
    }
}

extern "C" void kernel_launch(void* const* d_in, const int* in_sizes, int n_in,
                              void* d_out, int out_size, void* d_ws, size_t ws_size,
                              hipStream_t stream) {
    const float* x  = (const float*)d_in[0];
    const float* cb = (const float*)d_in[1];
    float* out = (float*)d_out;
    rvq_kernel<<<kItems / kBlock, kBlock, 0, stream>>>(x, cb, out);
}

// Round 2
// 1560.492 us; speedup vs baseline: 1.1745x; 1.1745x over previous
//
#include <hip/hip_runtime.h>
#include <math.h>

// Residual VQ: x (262144,128) fp32, codebooks (3,256,128) fp32.
// Output: [indices as float (262144*3)] ++ [quantized (262144*128)].
//
// ARITHMETIC CONTRACT (round 3, absmax=0 — do not change):
//   M_k  = OpenBLAS sgemm K-loop: sequential FMA chain j=0..127, acc init 0
//   A    = np.sum(r*r): pairwise_sum 8-accumulator scheme, products rounded
//          separately (fmaf(x,x,0) = single-rounded product, blocks fusion)
//   d2_k = (A - 2.0f*M_k) + B_k ; argmin strict < ascending k
//          (fmaf(-2,M,A)+B == (A-2.0f*M)+B bit-exact: 2*M exact, one rounding)
//   residual: r1 = x - q0 (1 rounding), r2 = r1 - q1 (1 rounding)
//          == fmaf(-1,q0,x), fmaf(-1,q1,r1) bit-exact
//   quantized = (q0 + q1) + q2 elementwise fp32, ref order
//
// ROUND 6 CHANGE: give up on keeping the 128-float residual live (rounds 4+5:
// allocator spills to ~88-104 VGPRs no matter what launch_bounds say; kernel
// stays scratch-latency-bound at VALUBusy 39%). New structure needs <=~80 live
// VGPRs: K_TILE=32 entries with NAMED accumulators m0..m31; the residual is
// RECOMPUTED per 8-dim chunk from r = x - q0 - q1 via masked FMAs (bit-exact,
// see above). No residual storage anywhere -> nothing to spill. FMA chains
// for each entry are suspended/resumed across chunks (same sequential chain,
// same rounding). A is accumulated in numpy's 8-stripe scheme during ktile 0.
// Codebook tile loads are wave-uniform -> scalar s_load (K$ holds exactly one
// 32x512B tile); x re-reads and q-row gathers are L2/L3-resident and overlap
// the ~365us FMA-issue floor. __launch_bounds__(256,4): VGPR budget 128,
// grid 1024 -> 4 blocks/CU -> 16 waves/CU.

constexpr int kItems = 262144;
constexpr int kDim   = 128;
constexpr int kNcb   = 3;
constexpr int kK     = 256;
constexpr int kBlock = 256;
constexpr int KT     = 32;          // entries per k-tile (named accumulators)
constexpr int NKT    = kK / KT;     // 8
constexpr int NJC    = kDim / 8;    // 16 chunks of 8 dims

__device__ __forceinline__ float sq_rn(float x) {
    return __builtin_fmaf(x, x, 0.0f);
}

// numpy pairwise_sum, n=128: 8 accumulators, acc_j = v[j]+v[j+8]+...+v[j+120],
// combined ((r0+r1)+(r2+r3))+((r4+r5)+(r6+r7)). Used for the LDS B-table.
template <typename F>
__device__ __forceinline__ float np_pairwise128(F term) {
    float r0 = term(0), r1 = term(1), r2 = term(2), r3 = term(3),
          r4 = term(4), r5 = term(5), r6 = term(6), r7 = term(7);
    #pragma unroll
    for (int i = 8; i < 128; i += 8) {
        r0 = r0 + term(i + 0); r1 = r1 + term(i + 1);
        r2 = r2 + term(i + 2); r3 = r3 + term(i + 3);
        r4 = r4 + term(i + 4); r5 = r5 + term(i + 5);
        r6 = r6 + term(i + 6); r7 = r7 + term(i + 7);
    }
    return ((r0 + r1) + (r2 + r3)) + ((r4 + r5) + (r6 + r7));
}

#define X32(X) X(0) X(1) X(2) X(3) X(4) X(5) X(6) X(7) \
  X(8) X(9) X(10) X(11) X(12) X(13) X(14) X(15) \
  X(16) X(17) X(18) X(19) X(20) X(21) X(22) X(23) \
  X(24) X(25) X(26) X(27) X(28) X(29) X(30) X(31)

__global__ __launch_bounds__(kBlock, 4) void rvq_kernel(
    const float* __restrict__ x,
    const float* __restrict__ cb,
    float* __restrict__ out)
{
    // B_k = np.sum(cb*cb, axis=-1), bit-exact, staged in LDS
    __shared__ float s_B[kNcb * kK];
    for (int m = threadIdx.x; m < kNcb * kK; m += kBlock) {
        const float* row = cb + (size_t)m * kDim;
        s_B[m] = np_pairwise128([&](int j) { return sq_rn(row[j]); });
    }
    __syncthreads();

    const int item = blockIdx.x * kBlock + threadIdx.x;
    const float4* xv = (const float4*)(x + (size_t)item * kDim);

    int sel0 = 0, sel1 = 0, sel2 = 0;

    for (int c = 0; c < kNcb; ++c) {
        const float* cbase = cb + (size_t)c * kK * kDim;
        // rows of previously selected codewords (divergent gathers, L2-hot).
        // For c==0 these read row 0 (uniform, broadcast-cheap) and are
        // neutralized by mask0/mask1 = 0 (fmaf(-0,w,x) == x except an
        // unobservable sign-of-zero; see contract notes).
        const float4* w0v = (const float4*)(cb + (size_t)sel0 * kDim);
        const float4* w1v = (const float4*)(cb + (size_t)(kK + sel1) * kDim);
        const float mask0 = (c >= 1) ? 1.0f : 0.0f;
        const float mask1 = (c >= 2) ? 1.0f : 0.0f;

        float a0 = 0.f, a1 = 0.f, a2 = 0.f, a3 = 0.f,
              a4 = 0.f, a5 = 0.f, a6 = 0.f, a7 = 0.f;
        float A = 0.0f;
        float best = INFINITY;
        int bi = 0;

        #pragma unroll 1
        for (int kt = 0; kt < NKT; ++kt) {
            const float* cbT = cbase + (size_t)kt * KT * kDim;

            #define MDECL(e) float m##e = 0.0f;
            X32(MDECL)
            #undef MDECL

            #pragma unroll 1
            for (int jc = 0; jc < NJC; ++jc) {
                // residual chunk r[8jc .. 8jc+7], recomputed bit-exactly
                const float4 xa  = xv[2*jc],  xb  = xv[2*jc+1];
                const float4 wa0 = w0v[2*jc], wb0 = w0v[2*jc+1];
                const float4 wa1 = w1v[2*jc], wb1 = w1v[2*jc+1];
                float rr0 = __builtin_fmaf(-mask0, wa0.x, xa.x);
                float rr1 = __builtin_fmaf(-mask0, wa0.y, xa.y);
                float rr2 = __builtin_fmaf(-mask0, wa0.z, xa.z);
                float rr3 = __builtin_fmaf(-mask0, wa0.w, xa.w);
                float rr4 = __builtin_fmaf(-mask0, wb0.x, xb.x);
                float rr5 = __builtin_fmaf(-mask0, wb0.y, xb.y);
                float rr6 = __builtin_fmaf(-mask0, wb0.z, xb.z);
                float rr7 = __builtin_fmaf(-mask0, wb0.w, xb.w);
                rr0 = __builtin_fmaf(-mask1, wa1.x, rr0);
                rr1 = __builtin_fmaf(-mask1, wa1.y, rr1);
                rr2 = __builtin_fmaf(-mask1, wa1.z, rr2);
                rr3 = __builtin_fmaf(-mask1, wa1.w, rr3);
                rr4 = __builtin_fmaf(-mask1, wb1.x, rr4);
                rr5 = __builtin_fmaf(-mask1, wb1.y, rr5);
                rr6 = __builtin_fmaf(-mask1, wb1.z, rr6);
                rr7 = __builtin_fmaf(-mask1, wb1.w, rr7);

                // A accumulation: numpy 8-stripe scheme, only on first k-tile
                if (kt == 0) {
                    a0 = a0 + sq_rn(rr0); a1 = a1 + sq_rn(rr1);
                    a2 = a2 + sq_rn(rr2); a3 = a3 + sq_rn(rr3);
                    a4 = a4 + sq_rn(rr4); a5 = a5 + sq_rn(rr5);
                    a6 = a6 + sq_rn(rr6); a7 = a7 + sq_rn(rr7);
                }

                // 32 entries x 8 dims: resume each entry's sequential FMA chain
                #define MROW(e) { \
                    const float4* rp = (const float4*)(cbT + (size_t)(e) * kDim); \
                    const float4 ca = rp[2*jc], cd = rp[2*jc+1]; \
                    m##e = __builtin_fmaf(rr0, ca.x, m##e); \
                    m##e = __builtin_fmaf(rr1, ca.y, m##e); \
                    m##e = __builtin_fmaf(rr2, ca.z, m##e); \
                    m##e = __builtin_fmaf(rr3, ca.w, m##e); \
                    m##e = __builtin_fmaf(rr4, cd.x, m##e); \
                    m##e = __builtin_fmaf(rr5, cd.y, m##e); \
                    m##e = __builtin_fmaf(rr6, cd.z, m##e); \
                    m##e = __builtin_fmaf(rr7, cd.w, m##e); }
                X32(MROW)
                #undef MROW
            }

            if (kt == 0)
                A = ((a0 + a1) + (a2 + a3)) + ((a4 + a5) + (a6 + a7));

            const int kb = kt * KT;
            #define EPI(e) { \
                float t = __builtin_fmaf(-2.0f, m##e, A) + s_B[c * kK + kb + (e)]; \
                if (t < best) { best = t; bi = kb + (e); } }
            X32(EPI)
            #undef EPI
        }

        if (c == 0) sel0 = bi; else if (c == 1) sel1 = bi; else sel2 = bi;
    }

    // --- outputs
    float* out_idx = out;                             // (items, 3) as float
    float* out_q   = out + (size_t)kItems * kNcb;     // (items, 128)
    out_idx[(size_t)item * kNcb + 0] = (float)sel0;
    out_idx[(size_t)item * kNcb + 1] = (float)sel1;
    out_idx[(size_t)item * kNcb + 2] = (float)sel2;

    const float4* q0v = (const float4*)(cb + ((size_t)0 * kK + sel0) * kDim);
    const float4* q1v = (const float4*)(cb + ((size_t)1 * kK + sel1) * kDim);
    const float4* q2v = (const float4*)(cb + ((size_t)2 * kK + sel2) * kDim);
    float4* qov = (float4*)(out_q + (size_t)item * kDim);
    #pragma unroll
    for (int i = 0; i < kDim / 4; ++i) {
        const float4 u = q0v[i], v = q1v[i], w = q2v[i];
        float4 o;
        o.x = (u.x + v.x) + w.x;
        o.y = (u.y + v.y) + w.y;
        o.z = (u.z + v.z) + w.z;
        o.w = (u.w + v.w) + w.w;
        qov[i] = o;   // ((0+q0)+q1)+q2 in fp32, ref order
    }
}

extern "C" void kernel_launch(void* const* d_in, const int* in_sizes, int n_in,
                              void* d_out, int out_size, void* d_ws, size_t ws_size,
                              hipStream_t stream) {
    const float* x  = (const float*)d_in[0];
    const float* cb = (const float*)d_in[1];
    float* out = (float*)d_out;
    rvq_kernel<<<kItems / kBlock, kBlock, 0, stream>>>(x, cb, out);
}